// Round 14
// baseline (501.382 us; speedup 1.0000x reference)
//
#include <hip/hip_runtime.h>

#define N_NODES 100000
#define E_EDGES 1600000
#define D 64
#define NB 256                         // buckets
#define BW 391                         // bucket width: 391*256 = 100096 >= N
#define EPB 2048                       // edges per binning block
#define NBLK ((E_EDGES + EPB - 1) / EPB)   // 782
#define CAP 8192                       // per-bucket LDS staging capacity
#define CSR_STRIDE (E_EDGES + 64)

// ---- raw buffer load via hardware SRSRC (32-bit voffset, OOB clamps to 0)
// word3 = 0x00020000 REQUIRED for raw untyped dword access (round-9 lesson).
__device__ __forceinline__ __amdgpu_buffer_rsrc_t make_rsrc(const void* p, unsigned bytes) {
    return __builtin_amdgcn_make_buffer_rsrc(const_cast<void*>(p), (short)0,
                                             (int)bytes, 0x00020000);
}
__device__ __forceinline__ unsigned buf_ld(__amdgpu_buffer_rsrc_t r, int voff) {
    return __builtin_amdgcn_raw_buffer_load_b32(r, voff, 0, 0);
}

// ---- kA: per-block per-bucket histogram (coalesced writes, LDS atomics only)
__global__ __launch_bounds__(256) void hist_kernel(
    const int* __restrict__ dst0, const int* __restrict__ dst1, const int* __restrict__ dst2,
    unsigned* __restrict__ bh) {
    __shared__ unsigned h[NB];
    int t = threadIdx.x, blk = blockIdx.x, e = blockIdx.y;
    const int* dst = (e == 0) ? dst0 : (e == 1) ? dst1 : dst2;
    h[t] = 0;
    __syncthreads();
    int base = blk * EPB;
    #pragma unroll
    for (int r = 0; r < EPB / 256; ++r) {
        int i = base + r * 256 + t;
        if (i < E_EDGES) atomicAdd(&h[(unsigned)dst[i] / BW], 1u);
    }
    __syncthreads();
    bh[((size_t)e * NBLK + blk) * NB + t] = h[t];
}

// ---- kB: exclusive scan down each bucket column of bh (in place) + bucket totals
__global__ __launch_bounds__(256) void colscan_kernel(
    unsigned* __restrict__ bh, unsigned* __restrict__ total) {
    __shared__ unsigned sa[1024], sb[1024];
    int t = threadIdx.x, b = blockIdx.x, e = blockIdx.y;
    unsigned orig[4];
    #pragma unroll
    for (int k = 0; k < 4; ++k) {
        int i = t + k * 256;
        unsigned v = (i < NBLK) ? bh[((size_t)e * NBLK + i) * NB + b] : 0u;
        orig[k] = v;
        sa[i] = v;
    }
    __syncthreads();
    unsigned* s = sa; unsigned* d = sb;
    for (int st = 1; st < 1024; st <<= 1) {
        #pragma unroll
        for (int k = 0; k < 4; ++k) {
            int i = t + k * 256;
            d[i] = s[i] + ((i >= st) ? s[i - st] : 0u);
        }
        __syncthreads();
        unsigned* tmp = s; s = d; d = tmp;
    }
    #pragma unroll
    for (int k = 0; k < 4; ++k) {
        int i = t + k * 256;
        if (i < NBLK) bh[((size_t)e * NBLK + i) * NB + b] = s[i] - orig[k];
    }
    if (t == 0) total[e * NB + b] = s[1023];
}

// ---- kC: bucket bases = exclusive scan of totals (per etype)
__global__ __launch_bounds__(256) void basescan_kernel(
    const unsigned* __restrict__ total, unsigned* __restrict__ bases) {
    __shared__ unsigned sa[NB], sb[NB];
    int t = threadIdx.x;
    for (int e = 0; e < 3; ++e) {
        unsigned v = total[e * NB + t];
        sa[t] = v;
        __syncthreads();
        unsigned* s = sa; unsigned* d = sb;
        for (int st = 1; st < NB; st <<= 1) {
            d[t] = s[t] + ((t >= st) ? s[t - st] : 0u);
            __syncthreads();
            unsigned* tmp = s; s = d; d = tmp;
        }
        bases[e * NB + t] = s[t] - v;
        __syncthreads();
    }
}

// ---- kD: binning scatter; pos = base + block-offset + LDS rank; packed {dloc,src}
__global__ __launch_bounds__(256) void bin_kernel(
    const int* __restrict__ s0, const int* __restrict__ s1, const int* __restrict__ s2,
    const int* __restrict__ d0, const int* __restrict__ d1, const int* __restrict__ d2,
    const unsigned* __restrict__ bh, const unsigned* __restrict__ bases,
    unsigned* __restrict__ binned) {
    __shared__ unsigned basel[NB];
    __shared__ unsigned lc[NB];
    int t = threadIdx.x, blk = blockIdx.x, e = blockIdx.y;
    const int* src_ = (e == 0) ? s0 : (e == 1) ? s1 : s2;
    const int* dst_ = (e == 0) ? d0 : (e == 1) ? d1 : d2;
    basel[t] = bases[e * NB + t] + bh[((size_t)e * NBLK + blk) * NB + t];
    lc[t] = 0;
    __syncthreads();
    int base = blk * EPB;
    #pragma unroll
    for (int r = 0; r < EPB / 256; ++r) {
        int i = base + r * 256 + t;
        if (i < E_EDGES) {
            unsigned dd = (unsigned)dst_[i];
            unsigned b = dd / BW;
            unsigned dloc = dd - b * BW;
            unsigned rank = atomicAdd(&lc[b], 1u);
            binned[(size_t)e * E_EDGES + basel[b] + rank] = (unsigned)src_[i] | (dloc << 17);
        }
    }
}

// ---- kE: per-bucket CSR build fully in LDS, coalesced dump (grid.y = etype)
//      csr entries are PRE-SHIFTED row byte offsets: src*128  (R10 version, no sort)
__global__ __launch_bounds__(256) void csr_kernel(
    const unsigned* __restrict__ binned, const unsigned* __restrict__ total,
    const unsigned* __restrict__ bases, int* __restrict__ csr,
    unsigned* __restrict__ off, unsigned* __restrict__ cnt) {
    __shared__ unsigned lh[512], sa[512], sb[512];
    __shared__ unsigned loff[BW + 1], lc[BW + 1];
    __shared__ int cl[CAP];
    int t = threadIdx.x, b = blockIdx.x, e = blockIdx.y;
    unsigned n = total[e * NB + b];
    unsigned g = bases[e * NB + b];
    lh[t] = 0; lh[t + 256] = 0;
    for (int j = t; j < BW + 1; j += 256) lc[j] = 0;
    __syncthreads();
    const unsigned* bp = binned + (size_t)e * E_EDGES + g;
    for (unsigned i = t; i < n; i += 256) atomicAdd(&lh[bp[i] >> 17], 1u);
    __syncthreads();
    sa[t] = lh[t]; sa[t + 256] = lh[t + 256];
    __syncthreads();
    unsigned* s = sa; unsigned* d = sb;
    for (int st = 1; st < 512; st <<= 1) {
        d[t] = s[t] + ((t >= st) ? s[t - st] : 0u);
        int i2 = t + 256;
        d[i2] = s[i2] + ((i2 >= st) ? s[i2 - st] : 0u);
        __syncthreads();
        unsigned* tmp = s; s = d; d = tmp;
    }
    if (t < BW + 1 - 256) loff[t + 256] = s[t + 256] - lh[t + 256];
    loff[t] = s[t] - lh[t];
    __syncthreads();
    int* csre = csr + (size_t)e * CSR_STRIDE;
    if (n <= CAP) {
        for (unsigned i = t; i < n; i += 256) {
            unsigned v = bp[i];
            unsigned dl = v >> 17;
            unsigned r = atomicAdd(&lc[dl], 1u);
            cl[loff[dl] + r] = (int)((v & 0x1FFFFu) << 7);
        }
        __syncthreads();
        for (unsigned i = t; i < n; i += 256) csre[g + i] = cl[i];
    } else {  // statistically impossible overflow fallback (correct, slower)
        for (unsigned i = t; i < n; i += 256) {
            unsigned v = bp[i];
            unsigned dl = v >> 17;
            unsigned r = atomicAdd(&lc[dl], 1u);
            csre[g + loff[dl] + r] = (int)((v & 0x1FFFFu) << 7);
        }
    }
    int node0 = b * BW;
    for (int j = t; j < BW; j += 256) {
        int nd = node0 + j;
        if (nd < N_NODES) {
            off[e * N_NODES + nd] = g + loff[j];
            cnt[e * N_NODES + nd] = lh[j];
        }
    }
}

// ---- convert x rows to packed bf16x2 (RNE): xh[n*32+p] = {bf16(x[2p]), bf16(x[2p+1])}
__global__ __launch_bounds__(256) void convert_kernel(const float* __restrict__ x,
                                                      unsigned* __restrict__ xh) {
    int i = blockIdx.x * 256 + threadIdx.x;
    float2 v = *reinterpret_cast<const float2*>(x + (size_t)i * 2);
    unsigned lo = __float_as_uint(v.x), hi = __float_as_uint(v.y);
    lo = (lo + 0x7FFFu + ((lo >> 16) & 1u)) >> 16;
    hi = (hi + 0x7FFFu + ((hi >> 16) & 1u)) & 0xFFFF0000u;
    xh[i] = lo | hi;
}

#define UNPACK_ADD(u, s, tt) \
    s += __uint_as_float((u) << 16); tt += __uint_as_float((u) & 0xFFFF0000u);
#define UNPACK_FMA(m, u, s, tt) \
    s = fmaf(m, __uint_as_float((u) << 16), s); \
    tt = fmaf(m, __uint_as_float((u) & 0xFFFF0000u), tt);

// ---- fused gather+transform, all 3 etypes: half-wave (32 lanes) per node.
//      R14: all segment headers (off/cnt) + FIRST index block of each etype preloaded
//      before any gather; index blocks software-pipelined (prefetch b+1 during b).
__global__ __launch_bounds__(256) void gather_fused_kernel(
    const unsigned* __restrict__ xh, const int* __restrict__ csr,
    const unsigned* __restrict__ off, const unsigned* __restrict__ cnt,
    const float* __restrict__ W0, const float* __restrict__ W1, const float* __restrict__ W2,
    const float* __restrict__ b0, const float* __restrict__ b1, const float* __restrict__ b2,
    float* __restrict__ out) {
    __shared__ float aggL[3][8][D];
    __shared__ int cntL[3][8];

    int tid = threadIdx.x;
    int hw = tid >> 5, l = tid & 31;       // half-wave id (node slot), lane-in-half
    int wv = tid >> 6, lane = tid & 63;    // wave id, lane (transform phase)
    int nodebase = blockIdx.x * 8;
    int node = nodebase + hw;
    int l4 = l * 4;

    __amdgpu_buffer_rsrc_t srd = make_rsrc(xh, N_NODES * D * 2);   // bf16 table, bytes

    // ---- hoisted headers: all 3 etypes' cnt/off issue together
    unsigned cc[3];
    const int* ix[3];
    #pragma unroll
    for (int e = 0; e < 3; ++e) {
        cc[e] = cnt[e * N_NODES + node];
        ix[e] = csr + (size_t)e * CSR_STRIDE + off[e * N_NODES + node];
    }
    // ---- preload FIRST index block of every etype (reads past segment end land in
    //      neighbor entries: valid in-bounds row offsets, masked by count below)
    int f[3][8];
    #pragma unroll
    for (int e = 0; e < 3; ++e) {
        #pragma unroll
        for (int j = 0; j < 8; ++j) f[e][j] = ix[e][j];
    }

    #pragma unroll
    for (int e = 0; e < 3; ++e) {
        unsigned c = cc[e];
        const int* idx = ix[e];

        float s0 = 0.f, s1 = 0.f, s2 = 0.f, s3 = 0.f;
        float s4 = 0.f, s5 = 0.f, s6 = 0.f, s7 = 0.f;
        float t0 = 0.f, t1 = 0.f, t2 = 0.f, t3 = 0.f;
        float t4 = 0.f, t5 = 0.f, t6 = 0.f, t7 = 0.f;

        int c0 = f[e][0], c1 = f[e][1], c2 = f[e][2], c3 = f[e][3];
        int c4 = f[e][4], c5 = f[e][5], c6 = f[e][6], c7 = f[e][7];

        unsigned fb = c >> 3;                // full 8-blocks
        for (unsigned blk = 0; blk < fb; ++blk) {
            // prefetch next index block (tail block or harmless past-end read)
            const int* np = idx + (blk + 1) * 8;
            int n0 = np[0], n1 = np[1], n2 = np[2], n3 = np[3];
            int n4 = np[4], n5 = np[5], n6 = np[6], n7 = np[7];
            unsigned u0 = buf_ld(srd, c0 + l4);
            unsigned u1 = buf_ld(srd, c1 + l4);
            unsigned u2 = buf_ld(srd, c2 + l4);
            unsigned u3 = buf_ld(srd, c3 + l4);
            unsigned u4 = buf_ld(srd, c4 + l4);
            unsigned u5 = buf_ld(srd, c5 + l4);
            unsigned u6 = buf_ld(srd, c6 + l4);
            unsigned u7 = buf_ld(srd, c7 + l4);
            UNPACK_ADD(u0, s0, t0) UNPACK_ADD(u1, s1, t1)
            UNPACK_ADD(u2, s2, t2) UNPACK_ADD(u3, s3, t3)
            UNPACK_ADD(u4, s4, t4) UNPACK_ADD(u5, s5, t5)
            UNPACK_ADD(u6, s6, t6) UNPACK_ADD(u7, s7, t7)
            c0 = n0; c1 = n1; c2 = n2; c3 = n3;
            c4 = n4; c5 = n5; c6 = n6; c7 = n7;
        }
        if (c & 7) {                          // one predicated 8-wide tail block
            unsigned j = fb * 8;              // current regs already hold tail indices
            unsigned u0 = buf_ld(srd, c0 + l4);
            unsigned u1 = buf_ld(srd, c1 + l4);
            unsigned u2 = buf_ld(srd, c2 + l4);
            unsigned u3 = buf_ld(srd, c3 + l4);
            unsigned u4 = buf_ld(srd, c4 + l4);
            unsigned u5 = buf_ld(srd, c5 + l4);
            unsigned u6 = buf_ld(srd, c6 + l4);
            unsigned u7 = buf_ld(srd, c7 + l4);
            float m0 = (j + 0 < c) ? 1.f : 0.f;
            float m1 = (j + 1 < c) ? 1.f : 0.f;
            float m2 = (j + 2 < c) ? 1.f : 0.f;
            float m3 = (j + 3 < c) ? 1.f : 0.f;
            float m4 = (j + 4 < c) ? 1.f : 0.f;
            float m5 = (j + 5 < c) ? 1.f : 0.f;
            float m6 = (j + 6 < c) ? 1.f : 0.f;
            float m7 = (j + 7 < c) ? 1.f : 0.f;
            UNPACK_FMA(m0, u0, s0, t0) UNPACK_FMA(m1, u1, s1, t1)
            UNPACK_FMA(m2, u2, s2, t2) UNPACK_FMA(m3, u3, s3, t3)
            UNPACK_FMA(m4, u4, s4, t4) UNPACK_FMA(m5, u5, s5, t5)
            UNPACK_FMA(m6, u6, s6, t6) UNPACK_FMA(m7, u7, s7, t7)
        }
        float sc = c ? 1.0f / (float)c : 0.0f;
        float m0 = (((s0 + s1) + (s2 + s3)) + ((s4 + s5) + (s6 + s7))) * sc;
        float m1 = (((t0 + t1) + (t2 + t3)) + ((t4 + t5) + (t6 + t7))) * sc;
        *reinterpret_cast<float2*>(&aggL[e][hw][2 * l]) = make_float2(m0, m1);
        if (l == 0) cntL[e][hw] = (int)c;
    }
    __syncthreads();

    // ---- transform: wave wv handles nodes 2wv, 2wv+1; lane = output column; all 3 etypes
    float acc0 = 0.f, acc1 = 0.f;
    #pragma unroll
    for (int e = 0; e < 3; ++e) {
        const float* W = (e == 0) ? W0 : (e == 1) ? W1 : W2;
        const float* bias = (e == 0) ? b0 : (e == 1) ? b1 : b2;
        float a0 = 0.f, a1 = 0.f;
        #pragma unroll
        for (int k = 0; k < D; ++k) {
            float wk = W[k * D + lane];
            a0 = fmaf(aggL[e][2 * wv][k], wk, a0);
            a1 = fmaf(aggL[e][2 * wv + 1][k], wk, a1);
        }
        float bl = bias[lane];
        if (cntL[e][2 * wv] > 0)     acc0 += a0 + bl;
        if (cntL[e][2 * wv + 1] > 0) acc1 += a1 + bl;
    }

    size_t o0 = (size_t)(nodebase + 2 * wv) * D + lane;
    out[o0] = acc0;
    out[o0 + D] = acc1;
}

extern "C" void kernel_launch(void* const* d_in, const int* in_sizes, int n_in,
                              void* d_out, int out_size, void* d_ws, size_t ws_size,
                              hipStream_t stream) {
    const float* x = (const float*)d_in[0];
    const float* W[3] = {(const float*)d_in[1], (const float*)d_in[5], (const float*)d_in[9]};
    const float* b[3] = {(const float*)d_in[2], (const float*)d_in[6], (const float*)d_in[10]};
    const int* src[3] = {(const int*)d_in[3], (const int*)d_in[7], (const int*)d_in[11]};
    const int* dst[3] = {(const int*)d_in[4], (const int*)d_in[8], (const int*)d_in[12]};
    float* out = (float*)d_out;

    char* ws = (char*)d_ws;
    size_t o = 0;
    unsigned* bh = (unsigned*)(ws + o);     o += (size_t)3 * NBLK * NB * 4;   // 2.4 MB
    unsigned* total = (unsigned*)(ws + o);  o += (size_t)3 * NB * 4;
    unsigned* bases = (unsigned*)(ws + o);  o += (size_t)3 * NB * 4;
    unsigned* binned = (unsigned*)(ws + o); o += (size_t)3 * E_EDGES * 4;     // 19.2 MB
    unsigned* xh = binned;                  // overlay: binned dead after csr_kernel
    int* csr = (int*)(ws + o);              o += (size_t)3 * CSR_STRIDE * 4;  // 19.2 MB
    unsigned* off = (unsigned*)(ws + o);    o += (size_t)3 * N_NODES * 4;
    unsigned* cnt = (unsigned*)(ws + o);    o += (size_t)3 * N_NODES * 4;

    dim3 gE(NBLK, 3);
    hist_kernel<<<gE, 256, 0, stream>>>(dst[0], dst[1], dst[2], bh);
    dim3 gC(NB, 3);
    colscan_kernel<<<gC, 256, 0, stream>>>(bh, total);
    basescan_kernel<<<1, 256, 0, stream>>>(total, bases);
    bin_kernel<<<gE, 256, 0, stream>>>(src[0], src[1], src[2], dst[0], dst[1], dst[2],
                                       bh, bases, binned);
    dim3 gK(NB, 3);
    csr_kernel<<<gK, 256, 0, stream>>>(binned, total, bases, csr, off, cnt);
    convert_kernel<<<N_NODES * 32 / 256, 256, 0, stream>>>(x, xh);
    gather_fused_kernel<<<N_NODES / 8, 256, 0, stream>>>(xh, csr, off, cnt,
                                                         W[0], W[1], W[2], b[0], b[1], b[2], out);
}

// Round 15
// 277.545 us; speedup vs baseline: 1.8065x; 1.8065x over previous
//
#include <hip/hip_runtime.h>

#define N_NODES 100000
#define E_EDGES 1600000
#define D 64
#define NB 256                         // buckets
#define BW 391                         // bucket width: 391*256 = 100096 >= N
#define EPB 2048                       // edges per binning block
#define NBLK ((E_EDGES + EPB - 1) / EPB)   // 782
#define CAP 8192                       // per-bucket LDS staging capacity
#define CSR_STRIDE (E_EDGES + 64)

// ---- raw buffer load via hardware SRSRC (32-bit voffset, OOB clamps to 0)
// word3 = 0x00020000 is REQUIRED for raw untyped dword access (cdna4_isa SRD layout);
// flags=0 makes an invalid descriptor whose loads all return 0 (round-9 failure).
__device__ __forceinline__ __amdgpu_buffer_rsrc_t make_rsrc(const void* p, unsigned bytes) {
    return __builtin_amdgcn_make_buffer_rsrc(const_cast<void*>(p), /*stride*/(short)0,
                                             /*num_records*/(int)bytes,
                                             /*flags(word3)*/0x00020000);
}
__device__ __forceinline__ unsigned buf_ld(__amdgpu_buffer_rsrc_t r, int voff) {
    return __builtin_amdgcn_raw_buffer_load_b32(r, voff, 0, 0);
}

// ---- kA: per-block per-bucket histogram (coalesced writes, LDS atomics only)
__global__ __launch_bounds__(256) void hist_kernel(
    const int* __restrict__ dst0, const int* __restrict__ dst1, const int* __restrict__ dst2,
    unsigned* __restrict__ bh) {
    __shared__ unsigned h[NB];
    int t = threadIdx.x, blk = blockIdx.x, e = blockIdx.y;
    const int* dst = (e == 0) ? dst0 : (e == 1) ? dst1 : dst2;
    h[t] = 0;
    __syncthreads();
    int base = blk * EPB;
    #pragma unroll
    for (int r = 0; r < EPB / 256; ++r) {
        int i = base + r * 256 + t;
        if (i < E_EDGES) atomicAdd(&h[(unsigned)dst[i] / BW], 1u);
    }
    __syncthreads();
    bh[((size_t)e * NBLK + blk) * NB + t] = h[t];
}

// ---- kB: exclusive scan down each bucket column of bh (in place) + bucket totals
__global__ __launch_bounds__(256) void colscan_kernel(
    unsigned* __restrict__ bh, unsigned* __restrict__ total) {
    __shared__ unsigned sa[1024], sb[1024];
    int t = threadIdx.x, b = blockIdx.x, e = blockIdx.y;
    unsigned orig[4];
    #pragma unroll
    for (int k = 0; k < 4; ++k) {
        int i = t + k * 256;
        unsigned v = (i < NBLK) ? bh[((size_t)e * NBLK + i) * NB + b] : 0u;
        orig[k] = v;
        sa[i] = v;
    }
    __syncthreads();
    unsigned* s = sa; unsigned* d = sb;
    for (int st = 1; st < 1024; st <<= 1) {
        #pragma unroll
        for (int k = 0; k < 4; ++k) {
            int i = t + k * 256;
            d[i] = s[i] + ((i >= st) ? s[i - st] : 0u);
        }
        __syncthreads();
        unsigned* tmp = s; s = d; d = tmp;
    }
    #pragma unroll
    for (int k = 0; k < 4; ++k) {
        int i = t + k * 256;
        if (i < NBLK) bh[((size_t)e * NBLK + i) * NB + b] = s[i] - orig[k];
    }
    if (t == 0) total[e * NB + b] = s[1023];
}

// ---- kC: bucket bases = exclusive scan of totals (per etype)
__global__ __launch_bounds__(256) void basescan_kernel(
    const unsigned* __restrict__ total, unsigned* __restrict__ bases) {
    __shared__ unsigned sa[NB], sb[NB];
    int t = threadIdx.x;
    for (int e = 0; e < 3; ++e) {
        unsigned v = total[e * NB + t];
        sa[t] = v;
        __syncthreads();
        unsigned* s = sa; unsigned* d = sb;
        for (int st = 1; st < NB; st <<= 1) {
            d[t] = s[t] + ((t >= st) ? s[t - st] : 0u);
            __syncthreads();
            unsigned* tmp = s; s = d; d = tmp;
        }
        bases[e * NB + t] = s[t] - v;
        __syncthreads();
    }
}

// ---- kD: binning scatter; pos = base + block-offset + LDS rank; packed {dloc,src}
__global__ __launch_bounds__(256) void bin_kernel(
    const int* __restrict__ s0, const int* __restrict__ s1, const int* __restrict__ s2,
    const int* __restrict__ d0, const int* __restrict__ d1, const int* __restrict__ d2,
    const unsigned* __restrict__ bh, const unsigned* __restrict__ bases,
    unsigned* __restrict__ binned) {
    __shared__ unsigned basel[NB];
    __shared__ unsigned lc[NB];
    int t = threadIdx.x, blk = blockIdx.x, e = blockIdx.y;
    const int* src_ = (e == 0) ? s0 : (e == 1) ? s1 : s2;
    const int* dst_ = (e == 0) ? d0 : (e == 1) ? d1 : d2;
    basel[t] = bases[e * NB + t] + bh[((size_t)e * NBLK + blk) * NB + t];
    lc[t] = 0;
    __syncthreads();
    int base = blk * EPB;
    #pragma unroll
    for (int r = 0; r < EPB / 256; ++r) {
        int i = base + r * 256 + t;
        if (i < E_EDGES) {
            unsigned dd = (unsigned)dst_[i];
            unsigned b = dd / BW;
            unsigned dloc = dd - b * BW;
            unsigned rank = atomicAdd(&lc[b], 1u);
            binned[(size_t)e * E_EDGES + basel[b] + rank] = (unsigned)src_[i] | (dloc << 17);
        }
    }
}

// ---- kE: per-bucket CSR build fully in LDS, coalesced dump (grid.y = etype)
//      csr entries are PRE-SHIFTED row byte offsets: src*128
__global__ __launch_bounds__(256) void csr_kernel(
    const unsigned* __restrict__ binned, const unsigned* __restrict__ total,
    const unsigned* __restrict__ bases, int* __restrict__ csr,
    unsigned* __restrict__ off, unsigned* __restrict__ cnt) {
    __shared__ unsigned lh[512], sa[512], sb[512];
    __shared__ unsigned loff[BW + 1], lc[BW + 1];
    __shared__ int cl[CAP];
    int t = threadIdx.x, b = blockIdx.x, e = blockIdx.y;
    unsigned n = total[e * NB + b];
    unsigned g = bases[e * NB + b];
    lh[t] = 0; lh[t + 256] = 0;
    for (int j = t; j < BW + 1; j += 256) lc[j] = 0;
    __syncthreads();
    const unsigned* bp = binned + (size_t)e * E_EDGES + g;
    for (unsigned i = t; i < n; i += 256) atomicAdd(&lh[bp[i] >> 17], 1u);
    __syncthreads();
    sa[t] = lh[t]; sa[t + 256] = lh[t + 256];
    __syncthreads();
    unsigned* s = sa; unsigned* d = sb;
    for (int st = 1; st < 512; st <<= 1) {
        d[t] = s[t] + ((t >= st) ? s[t - st] : 0u);
        int i2 = t + 256;
        d[i2] = s[i2] + ((i2 >= st) ? s[i2 - st] : 0u);
        __syncthreads();
        unsigned* tmp = s; s = d; d = tmp;
    }
    if (t < BW + 1 - 256) loff[t + 256] = s[t + 256] - lh[t + 256];
    loff[t] = s[t] - lh[t];
    __syncthreads();
    int* csre = csr + (size_t)e * CSR_STRIDE;
    if (n <= CAP) {
        for (unsigned i = t; i < n; i += 256) {
            unsigned v = bp[i];
            unsigned dl = v >> 17;
            unsigned r = atomicAdd(&lc[dl], 1u);
            cl[loff[dl] + r] = (int)((v & 0x1FFFFu) << 7);
        }
        __syncthreads();
        for (unsigned i = t; i < n; i += 256) csre[g + i] = cl[i];
    } else {  // statistically impossible overflow fallback (correct, slower)
        for (unsigned i = t; i < n; i += 256) {
            unsigned v = bp[i];
            unsigned dl = v >> 17;
            unsigned r = atomicAdd(&lc[dl], 1u);
            csre[g + loff[dl] + r] = (int)((v & 0x1FFFFu) << 7);
        }
    }
    int node0 = b * BW;
    for (int j = t; j < BW; j += 256) {
        int nd = node0 + j;
        if (nd < N_NODES) {
            off[e * N_NODES + nd] = g + loff[j];
            cnt[e * N_NODES + nd] = lh[j];
        }
    }
}

// ---- convert x rows to packed bf16x2 (RNE): xh[n*32+p] = {bf16(x[2p]), bf16(x[2p+1])}
__global__ __launch_bounds__(256) void convert_kernel(const float* __restrict__ x,
                                                      unsigned* __restrict__ xh) {
    int i = blockIdx.x * 256 + threadIdx.x;    // pair index; grid covers N*32 exactly
    float2 v = *reinterpret_cast<const float2*>(x + (size_t)i * 2);
    unsigned lo = __float_as_uint(v.x), hi = __float_as_uint(v.y);
    lo = (lo + 0x7FFFu + ((lo >> 16) & 1u)) >> 16;
    hi = (hi + 0x7FFFu + ((hi >> 16) & 1u)) & 0xFFFF0000u;
    xh[i] = lo | hi;
}

#define UNPACK_ADD(u, s, tt) \
    s += __uint_as_float((u) << 16); tt += __uint_as_float((u) & 0xFFFF0000u);
#define UNPACK_FMA(m, u, s, tt) \
    s = fmaf(m, __uint_as_float((u) << 16), s); \
    tt = fmaf(m, __uint_as_float((u) & 0xFFFF0000u), tt);

// ---- fused gather+transform, all 3 etypes: half-wave (32 lanes) per node, lane = feature pair
__global__ __launch_bounds__(256) void gather_fused_kernel(
    const unsigned* __restrict__ xh, const int* __restrict__ csr,
    const unsigned* __restrict__ off, const unsigned* __restrict__ cnt,
    const float* __restrict__ W0, const float* __restrict__ W1, const float* __restrict__ W2,
    const float* __restrict__ b0, const float* __restrict__ b1, const float* __restrict__ b2,
    float* __restrict__ out) {
    __shared__ float aggL[3][8][D];
    __shared__ int cntL[3][8];

    int tid = threadIdx.x;
    int hw = tid >> 5, l = tid & 31;       // half-wave id (node slot), lane-in-half
    int wv = tid >> 6, lane = tid & 63;    // wave id, lane (transform phase)
    int nodebase = blockIdx.x * 8;
    int node = nodebase + hw;
    int l4 = l * 4;

    __amdgpu_buffer_rsrc_t srd = make_rsrc(xh, N_NODES * D * 2);   // bf16 table, bytes

    // ---- chase all 3 etypes back-to-back (no barriers: loads overlap across etypes)
    #pragma unroll
    for (int e = 0; e < 3; ++e) {
        unsigned c = cnt[e * N_NODES + node];
        const int* idx = csr + (size_t)e * CSR_STRIDE + off[e * N_NODES + node];

        float s0 = 0.f, s1 = 0.f, s2 = 0.f, s3 = 0.f;
        float s4 = 0.f, s5 = 0.f, s6 = 0.f, s7 = 0.f;
        float t0 = 0.f, t1 = 0.f, t2 = 0.f, t3 = 0.f;
        float t4 = 0.f, t5 = 0.f, t6 = 0.f, t7 = 0.f;

        unsigned fb = c >> 3;                // full 8-blocks
        for (unsigned blk = 0; blk < fb; ++blk) {
            const int* ip = idx + blk * 8;
            int i0 = ip[0], i1 = ip[1], i2 = ip[2], i3 = ip[3];
            int i4 = ip[4], i5 = ip[5], i6 = ip[6], i7 = ip[7];
            unsigned u0 = buf_ld(srd, i0 + l4);
            unsigned u1 = buf_ld(srd, i1 + l4);
            unsigned u2 = buf_ld(srd, i2 + l4);
            unsigned u3 = buf_ld(srd, i3 + l4);
            unsigned u4 = buf_ld(srd, i4 + l4);
            unsigned u5 = buf_ld(srd, i5 + l4);
            unsigned u6 = buf_ld(srd, i6 + l4);
            unsigned u7 = buf_ld(srd, i7 + l4);
            UNPACK_ADD(u0, s0, t0) UNPACK_ADD(u1, s1, t1)
            UNPACK_ADD(u2, s2, t2) UNPACK_ADD(u3, s3, t3)
            UNPACK_ADD(u4, s4, t4) UNPACK_ADD(u5, s5, t5)
            UNPACK_ADD(u6, s6, t6) UNPACK_ADD(u7, s7, t7)
        }
        if (c & 7) {                          // one predicated 8-wide tail block
            unsigned j = fb * 8;
            const int* ip = idx + j;          // reads past segment land in pad/neighbor entries;
            int i0 = ip[0], i1 = ip[1], i2 = ip[2], i3 = ip[3];   // garbage offsets OOB-clamp to 0
            int i4 = ip[4], i5 = ip[5], i6 = ip[6], i7 = ip[7];
            unsigned u0 = buf_ld(srd, i0 + l4);
            unsigned u1 = buf_ld(srd, i1 + l4);
            unsigned u2 = buf_ld(srd, i2 + l4);
            unsigned u3 = buf_ld(srd, i3 + l4);
            unsigned u4 = buf_ld(srd, i4 + l4);
            unsigned u5 = buf_ld(srd, i5 + l4);
            unsigned u6 = buf_ld(srd, i6 + l4);
            unsigned u7 = buf_ld(srd, i7 + l4);
            float m0 = (j + 0 < c) ? 1.f : 0.f;
            float m1 = (j + 1 < c) ? 1.f : 0.f;
            float m2 = (j + 2 < c) ? 1.f : 0.f;
            float m3 = (j + 3 < c) ? 1.f : 0.f;
            float m4 = (j + 4 < c) ? 1.f : 0.f;
            float m5 = (j + 5 < c) ? 1.f : 0.f;
            float m6 = (j + 6 < c) ? 1.f : 0.f;
            float m7 = (j + 7 < c) ? 1.f : 0.f;
            UNPACK_FMA(m0, u0, s0, t0) UNPACK_FMA(m1, u1, s1, t1)
            UNPACK_FMA(m2, u2, s2, t2) UNPACK_FMA(m3, u3, s3, t3)
            UNPACK_FMA(m4, u4, s4, t4) UNPACK_FMA(m5, u5, s5, t5)
            UNPACK_FMA(m6, u6, s6, t6) UNPACK_FMA(m7, u7, s7, t7)
        }
        float sc = c ? 1.0f / (float)c : 0.0f;
        float m0 = (((s0 + s1) + (s2 + s3)) + ((s4 + s5) + (s6 + s7))) * sc;
        float m1 = (((t0 + t1) + (t2 + t3)) + ((t4 + t5) + (t6 + t7))) * sc;
        *reinterpret_cast<float2*>(&aggL[e][hw][2 * l]) = make_float2(m0, m1);
        if (l == 0) cntL[e][hw] = (int)c;
    }
    __syncthreads();

    // ---- transform: wave wv handles nodes 2wv, 2wv+1; lane = output column; all 3 etypes
    float acc0 = 0.f, acc1 = 0.f;
    #pragma unroll
    for (int e = 0; e < 3; ++e) {
        const float* W = (e == 0) ? W0 : (e == 1) ? W1 : W2;
        const float* bias = (e == 0) ? b0 : (e == 1) ? b1 : b2;
        float a0 = 0.f, a1 = 0.f;
        #pragma unroll
        for (int k = 0; k < D; ++k) {
            float wk = W[k * D + lane];
            a0 = fmaf(aggL[e][2 * wv][k], wk, a0);
            a1 = fmaf(aggL[e][2 * wv + 1][k], wk, a1);
        }
        float bl = bias[lane];
        if (cntL[e][2 * wv] > 0)     acc0 += a0 + bl;
        if (cntL[e][2 * wv + 1] > 0) acc1 += a1 + bl;
    }

    size_t o0 = (size_t)(nodebase + 2 * wv) * D + lane;
    out[o0] = acc0;
    out[o0 + D] = acc1;
}

extern "C" void kernel_launch(void* const* d_in, const int* in_sizes, int n_in,
                              void* d_out, int out_size, void* d_ws, size_t ws_size,
                              hipStream_t stream) {
    const float* x = (const float*)d_in[0];
    const float* W[3] = {(const float*)d_in[1], (const float*)d_in[5], (const float*)d_in[9]};
    const float* b[3] = {(const float*)d_in[2], (const float*)d_in[6], (const float*)d_in[10]};
    const int* src[3] = {(const int*)d_in[3], (const int*)d_in[7], (const int*)d_in[11]};
    const int* dst[3] = {(const int*)d_in[4], (const int*)d_in[8], (const int*)d_in[12]};
    float* out = (float*)d_out;

    char* ws = (char*)d_ws;
    size_t o = 0;
    unsigned* bh = (unsigned*)(ws + o);     o += (size_t)3 * NBLK * NB * 4;   // 2.4 MB
    unsigned* total = (unsigned*)(ws + o);  o += (size_t)3 * NB * 4;
    unsigned* bases = (unsigned*)(ws + o);  o += (size_t)3 * NB * 4;
    unsigned* binned = (unsigned*)(ws + o); o += (size_t)3 * E_EDGES * 4;     // 19.2 MB
    unsigned* xh = binned;                  // overlay: binned dead after csr_kernel
    int* csr = (int*)(ws + o);              o += (size_t)3 * CSR_STRIDE * 4;  // 19.2 MB
    unsigned* off = (unsigned*)(ws + o);    o += (size_t)3 * N_NODES * 4;
    unsigned* cnt = (unsigned*)(ws + o);    o += (size_t)3 * N_NODES * 4;

    dim3 gE(NBLK, 3);
    hist_kernel<<<gE, 256, 0, stream>>>(dst[0], dst[1], dst[2], bh);
    dim3 gC(NB, 3);
    colscan_kernel<<<gC, 256, 0, stream>>>(bh, total);
    basescan_kernel<<<1, 256, 0, stream>>>(total, bases);
    bin_kernel<<<gE, 256, 0, stream>>>(src[0], src[1], src[2], dst[0], dst[1], dst[2],
                                       bh, bases, binned);
    dim3 gK(NB, 3);
    csr_kernel<<<gK, 256, 0, stream>>>(binned, total, bases, csr, off, cnt);
    convert_kernel<<<N_NODES * 32 / 256, 256, 0, stream>>>(x, xh);
    gather_fused_kernel<<<N_NODES / 8, 256, 0, stream>>>(xh, csr, off, cnt,
                                                         W[0], W[1], W[2], b[0], b[1], b[2], out);
}